// Round 2
// baseline (399.258 us; speedup 1.0000x reference)
//
#include <hip/hip_runtime.h>
#include <hip/hip_bf16.h>

#define D_ 768
#define E_ 8
#define H_ 3072
#define N_TOK 4096
#define BM 128
#define BN 128
#define BK 32

typedef _Float16 f16;
typedef f16 f16x8 __attribute__((ext_vector_type(8)));
typedef float f32x4 __attribute__((ext_vector_type(4)));

__device__ __forceinline__ void gld16(const f16* g, f16* l) {
    __builtin_amdgcn_global_load_lds(
        (const __attribute__((address_space(1))) unsigned int*)g,
        (__attribute__((address_space(3))) unsigned int*)l, 16, 0, 0);
}

// ---------------- x -> fp16 ----------------
__global__ __launch_bounds__(256) void cvt_x(const float* __restrict__ x,
                                             f16* __restrict__ xh) {
    size_t i = ((size_t)blockIdx.x * 256 + threadIdx.x) * 8;
    float4 a = *(const float4*)(x + i);
    float4 b = *(const float4*)(x + i + 4);
    f16x8 o;
    o[0] = (f16)a.x; o[1] = (f16)a.y; o[2] = (f16)a.z; o[3] = (f16)a.w;
    o[4] = (f16)b.x; o[5] = (f16)b.y; o[6] = (f16)b.z; o[7] = (f16)b.w;
    *(f16x8*)(xh + i) = o;
}

// ---------------- weight convert + transpose: fp32 [R][C] -> fp16 [C][R] ----------------
__global__ __launch_bounds__(256) void cvt_w_t(const float* __restrict__ in,
                                               f16* __restrict__ outp,
                                               int R, int C) {
    __shared__ f16 t[64][66];
    const float* src = in + (size_t)blockIdx.z * R * C;
    f16* dst = outp + (size_t)blockIdx.z * R * C;
    int r0 = blockIdx.y * 64, c0 = blockIdx.x * 64;
    int tid = threadIdx.x;
#pragma unroll
    for (int i = 0; i < 16; i++) {
        int idx = i * 256 + tid;
        int r = idx >> 6, c = idx & 63;
        t[r][c] = (f16)src[(size_t)(r0 + r) * C + (c0 + c)];
    }
    __syncthreads();
#pragma unroll
    for (int i = 0; i < 16; i++) {
        int idx = i * 256 + tid;
        int c = idx >> 6, r = idx & 63;
        dst[(size_t)(c0 + c) * R + (r0 + r)] = t[r][c];
    }
}

// ---------------- router ----------------
__global__ __launch_bounds__(256) void router(const float* __restrict__ x,
                                              const float* __restrict__ gw,
                                              const float* __restrict__ gb,
                                              int* __restrict__ counts,
                                              int* __restrict__ list,
                                              float* __restrict__ wslot) {
    int wv = threadIdx.x >> 6;
    int lane = threadIdx.x & 63;
    int tok = blockIdx.x * 4 + wv;
    const float* xr = x + (size_t)tok * D_;
    float acc[E_];
#pragma unroll
    for (int e = 0; e < E_; e++) acc[e] = 0.f;
    for (int d = lane; d < D_; d += 64) {
        float v = xr[d];
        const float* g = gw + d * E_;
#pragma unroll
        for (int e = 0; e < E_; e++) acc[e] += v * g[e];
    }
#pragma unroll
    for (int e = 0; e < E_; e++) {
#pragma unroll
        for (int off = 32; off; off >>= 1) acc[e] += __shfl_xor(acc[e], off, 64);
    }
    if (lane == 0) {
        float v0 = -3.4e38f, v1 = -3.4e38f;
        int i0 = 0, i1 = 0;
#pragma unroll
        for (int e = 0; e < E_; e++) {
            float l = acc[e] + gb[e];
            if (l > v0) { v1 = v0; i1 = i0; v0 = l; i0 = e; }
            else if (l > v1) { v1 = l; i1 = e; }
        }
        float p1 = expf(v1 - v0);
        float s = 1.f + p1;
        int p0 = atomicAdd(&counts[i0], 1);
        list[i0 * N_TOK + p0] = tok * 2;
        int p1p = atomicAdd(&counts[i1], 1);
        list[i1 * N_TOK + p1p] = tok * 2 + 1;
        wslot[tok * 2] = 1.f / s;
        wslot[tok * 2 + 1] = p1 / s;
    }
}

// ---------------- GEMM1: h = gelu(x @ w1 + b1) ----------------
// A: gathered token rows (fp16, K=D_). B: w1t [E][H][D] (k-contiguous rows).
__global__ __launch_bounds__(256) void gemm1(const f16* __restrict__ xh,
                                             const f16* __restrict__ w1t,
                                             const float* __restrict__ b1,
                                             const int* __restrict__ counts,
                                             const int* __restrict__ list,
                                             f16* __restrict__ hbuf) {
    int e = blockIdx.z;
    int cnt = counts[e];
    int rb = blockIdx.y * BM;
    if (rb >= cnt) return;
    int cb = blockIdx.x * BN;

    __shared__ f16 Alds[BM][BK];
    __shared__ f16 Blds[BN][BK];
    __shared__ int ids[BM];

    int tid = threadIdx.x;
    int wv = tid >> 6, lane = tid & 63;
    if (tid < BM) {
        int idx = rb + tid;
        ids[tid] = (idx < cnt) ? list[e * N_TOK + idx] : -1;
    }
    __syncthreads();

    // staging instruction q = wv*2 + c : covers 16 rows, lane l -> row q*16+(l>>2), chunk (l&3)*8
    int q0 = wv * 2, q1 = q0 + 1;
    int sr0 = q0 * 16 + (lane >> 2), sr1 = q1 * 16 + (lane >> 2);
    int sc = (lane & 3) * 8;
    int id0 = ids[sr0], id1 = ids[sr1];
    int fb = ids[0];
    const f16* aptr0 = xh + (size_t)(((id0 >= 0) ? id0 : fb) >> 1) * D_ + sc;
    const f16* aptr1 = xh + (size_t)(((id1 >= 0) ? id1 : fb) >> 1) * D_ + sc;
    const f16* wbase = w1t + (size_t)e * H_ * D_;
    const f16* bptr0 = wbase + (size_t)(cb + sr0) * D_ + sc;
    const f16* bptr1 = wbase + (size_t)(cb + sr1) * D_ + sc;
    f16* al0 = &Alds[q0 * 16][0];
    f16* al1 = &Alds[q1 * 16][0];
    f16* bl0 = &Blds[q0 * 16][0];
    f16* bl1 = &Blds[q1 * 16][0];

    int wr = (wv >> 1) * 64, wc = (wv & 1) * 64;
    int fr = lane & 15, fk = (lane >> 4) * 8;

    f32x4 acc[4][4] = {};

    for (int kk = 0; kk < D_; kk += BK) {
        gld16(aptr0 + kk, al0);
        gld16(aptr1 + kk, al1);
        gld16(bptr0 + kk, bl0);
        gld16(bptr1 + kk, bl1);
        __syncthreads();

        f16x8 af[4], bf[4];
#pragma unroll
        for (int m = 0; m < 4; m++) af[m] = *(const f16x8*)&Alds[wr + m * 16 + fr][fk];
#pragma unroll
        for (int n = 0; n < 4; n++) bf[n] = *(const f16x8*)&Blds[wc + n * 16 + fr][fk];
#pragma unroll
        for (int m = 0; m < 4; m++)
#pragma unroll
            for (int n = 0; n < 4; n++)
                acc[m][n] = __builtin_amdgcn_mfma_f32_16x16x32_f16(af[m], bf[n], acc[m][n], 0, 0, 0);
        __syncthreads();
    }

#pragma unroll
    for (int n = 0; n < 4; n++) {
        int colg = cb + wc + n * 16 + fr;
        float bias = b1[e * H_ + colg];
#pragma unroll
        for (int m = 0; m < 4; m++) {
#pragma unroll
            for (int r = 0; r < 4; r++) {
                int rloc = wr + m * 16 + (lane >> 4) * 4 + r;
                int id = ids[rloc];
                if (id >= 0) {
                    float v = acc[m][n][r] + bias;
                    v = 0.5f * v * (1.f + erff(v * 0.70710678f));
                    hbuf[(size_t)id * H_ + colg] = (f16)v;
                }
            }
        }
    }
}

// ---------------- GEMM2: y = (h @ w2 + b2) * wslot, scatter-add ----------------
#define KSPLIT 2
#define KCH (H_ / KSPLIT)
__global__ __launch_bounds__(256) void gemm2(const f16* __restrict__ hbuf,
                                             const f16* __restrict__ w2t,
                                             const float* __restrict__ b2,
                                             const int* __restrict__ counts,
                                             const int* __restrict__ list,
                                             const float* __restrict__ wslot,
                                             float* __restrict__ out) {
    int e = blockIdx.z;
    int cnt = counts[e];
    int rb = blockIdx.y * BM;
    if (rb >= cnt) return;
    int cbz = blockIdx.x;
    int cb = (cbz % (D_ / BN)) * BN;
    int kz = cbz / (D_ / BN);
    int k0 = kz * KCH;

    __shared__ f16 Alds[BM][BK];
    __shared__ f16 Blds[BN][BK];
    __shared__ int ids[BM];

    int tid = threadIdx.x;
    int wv = tid >> 6, lane = tid & 63;
    if (tid < BM) {
        int idx = rb + tid;
        ids[tid] = (idx < cnt) ? list[e * N_TOK + idx] : -1;
    }
    __syncthreads();

    int q0 = wv * 2, q1 = q0 + 1;
    int sr0 = q0 * 16 + (lane >> 2), sr1 = q1 * 16 + (lane >> 2);
    int sc = (lane & 3) * 8;
    int id0 = ids[sr0], id1 = ids[sr1];
    int fb = ids[0];
    const f16* aptr0 = hbuf + (size_t)((id0 >= 0) ? id0 : fb) * H_ + k0 + sc;
    const f16* aptr1 = hbuf + (size_t)((id1 >= 0) ? id1 : fb) * H_ + k0 + sc;
    const f16* wbase = w2t + (size_t)e * D_ * H_;
    const f16* bptr0 = wbase + (size_t)(cb + sr0) * H_ + k0 + sc;
    const f16* bptr1 = wbase + (size_t)(cb + sr1) * H_ + k0 + sc;
    f16* al0 = &Alds[q0 * 16][0];
    f16* al1 = &Alds[q1 * 16][0];
    f16* bl0 = &Blds[q0 * 16][0];
    f16* bl1 = &Blds[q1 * 16][0];

    int wr = (wv >> 1) * 64, wc = (wv & 1) * 64;
    int fr = lane & 15, fk = (lane >> 4) * 8;

    f32x4 acc[4][4] = {};

    for (int kk = 0; kk < KCH; kk += BK) {
        gld16(aptr0 + kk, al0);
        gld16(aptr1 + kk, al1);
        gld16(bptr0 + kk, bl0);
        gld16(bptr1 + kk, bl1);
        __syncthreads();

        f16x8 af[4], bf[4];
#pragma unroll
        for (int m = 0; m < 4; m++) af[m] = *(const f16x8*)&Alds[wr + m * 16 + fr][fk];
#pragma unroll
        for (int n = 0; n < 4; n++) bf[n] = *(const f16x8*)&Blds[wc + n * 16 + fr][fk];
#pragma unroll
        for (int m = 0; m < 4; m++)
#pragma unroll
            for (int n = 0; n < 4; n++)
                acc[m][n] = __builtin_amdgcn_mfma_f32_16x16x32_f16(af[m], bf[n], acc[m][n], 0, 0, 0);
        __syncthreads();
    }

#pragma unroll
    for (int n = 0; n < 4; n++) {
        int colg = cb + wc + n * 16 + fr;
        float bias = (kz == 0) ? b2[e * D_ + colg] : 0.f;
#pragma unroll
        for (int m = 0; m < 4; m++) {
#pragma unroll
            for (int r = 0; r < 4; r++) {
                int rloc = wr + m * 16 + (lane >> 4) * 4 + r;
                int id = ids[rloc];
                if (id >= 0) {
                    float w = wslot[id];
                    float v = (acc[m][n][r] + bias) * w;
                    atomicAdd(&out[(size_t)(id >> 1) * D_ + colg], v);
                }
            }
        }
    }
}

extern "C" void kernel_launch(void* const* d_in, const int* in_sizes, int n_in,
                              void* d_out, int out_size, void* d_ws, size_t ws_size,
                              hipStream_t stream) {
    const float* x = (const float*)d_in[0];
    const float* gate_w = (const float*)d_in[1];
    const float* gate_b = (const float*)d_in[2];
    const float* w1 = (const float*)d_in[3];
    const float* b1 = (const float*)d_in[4];
    const float* w2 = (const float*)d_in[5];
    const float* b2 = (const float*)d_in[6];
    float* out = (float*)d_out;

    char* ws = (char*)d_ws;
    int* counts = (int*)ws;                           // 256 B
    int* list = (int*)(ws + 1024);                    // 131072 B
    float* wslot = (float*)(ws + 132096);             // 32768 B
    f16* xh = (f16*)(ws + 196608);                    // 6291456 B
    f16* w1t = (f16*)(ws + 6488064);                  // 37748736 B
    f16* w2t = (f16*)(ws + 44236800);                 // 37748736 B
    f16* hbuf = (f16*)(ws + 81985536);                // 50331648 B  (end ~126.2 MiB)

    hipMemsetAsync(counts, 0, 256, stream);
    hipMemsetAsync(out, 0, (size_t)out_size * sizeof(float), stream);

    cvt_x<<<1536, 256, 0, stream>>>(x, xh);
    router<<<1024, 256, 0, stream>>>(x, gate_w, gate_b, counts, list, wslot);
    // w1 [E][D][H] fp32 -> w1t [E][H][D] fp16
    cvt_w_t<<<dim3(H_ / 64, D_ / 64, E_), 256, 0, stream>>>(w1, w1t, D_, H_);
    // w2 [E][H][D] fp32 -> w2t [E][D][H] fp16
    cvt_w_t<<<dim3(D_ / 64, H_ / 64, E_), 256, 0, stream>>>(w2, w2t, H_, D_);
    gemm1<<<dim3(H_ / BN, N_TOK / BM, E_), 256, 0, stream>>>(xh, w1t, b1, counts, list, hbuf);
    gemm2<<<dim3((D_ / BN) * KSPLIT, N_TOK / BM, E_), 256, 0, stream>>>(hbuf, w2t, b2, counts, list, wslot, out);
}

// Round 4
// 390.812 us; speedup vs baseline: 1.0216x; 1.0216x over previous
//
#include <hip/hip_runtime.h>
#include <hip/hip_bf16.h>

#define D_ 768
#define E_ 8
#define H_ 3072
#define N_TOK 4096
#define BM 128
#define BN 128
#define BK 32
#define PADK 40  // 32 + 8 halfs: breaks 64B-stride bank aliasing, keeps 16B align

typedef _Float16 f16;
typedef f16 f16x8 __attribute__((ext_vector_type(8)));
typedef float f32x4 __attribute__((ext_vector_type(4)));

// ---------------- x -> fp16 ----------------
__global__ __launch_bounds__(256) void cvt_x(const float* __restrict__ x,
                                             f16* __restrict__ xh) {
    size_t i = ((size_t)blockIdx.x * 256 + threadIdx.x) * 8;
    float4 a = *(const float4*)(x + i);
    float4 b = *(const float4*)(x + i + 4);
    f16x8 o;
    o[0] = (f16)a.x; o[1] = (f16)a.y; o[2] = (f16)a.z; o[3] = (f16)a.w;
    o[4] = (f16)b.x; o[5] = (f16)b.y; o[6] = (f16)b.z; o[7] = (f16)b.w;
    *(f16x8*)(xh + i) = o;
}

// ---------------- weight convert + transpose: fp32 [R][C] -> fp16 [C][R] ----------------
#define TP 66
__global__ __launch_bounds__(256) void cvt_w_t(const float* __restrict__ in,
                                               f16* __restrict__ outp,
                                               int R, int C) {
    __shared__ f16 t[64][TP];
    const float* src = in + (size_t)blockIdx.z * R * C;
    f16* dst = outp + (size_t)blockIdx.z * R * C;
    int r0 = blockIdx.y * 64, c0 = blockIdx.x * 64;
    int tid = threadIdx.x;
    {
        int r = tid >> 4;
        int c = (tid & 15) * 4;
#pragma unroll
        for (int i = 0; i < 4; i++) {
            float4 v = *(const float4*)(src + (size_t)(r0 + r + i * 16) * C + (c0 + c));
            t[r + i * 16][c] = (f16)v.x;
            t[r + i * 16][c + 1] = (f16)v.y;
            t[r + i * 16][c + 2] = (f16)v.z;
            t[r + i * 16][c + 3] = (f16)v.w;
        }
    }
    __syncthreads();
    {
        int c = tid >> 3;
        int rr = (tid & 7) * 8;
#pragma unroll
        for (int i = 0; i < 2; i++) {
            int cc = c + i * 32;
            f16x8 o;
#pragma unroll
            for (int j = 0; j < 8; j++) o[j] = t[rr + j][cc];
            *(f16x8*)(dst + (size_t)(c0 + cc) * R + (r0 + rr)) = o;
        }
    }
}

// ---------------- router ----------------
__global__ __launch_bounds__(256) void router(const float* __restrict__ x,
                                              const float* __restrict__ gw,
                                              const float* __restrict__ gb,
                                              int* __restrict__ counts,
                                              int* __restrict__ list,
                                              float* __restrict__ wslot) {
    int wv = threadIdx.x >> 6;
    int lane = threadIdx.x & 63;
    int tok = blockIdx.x * 4 + wv;
    const float* xr = x + (size_t)tok * D_;
    float acc[E_];
#pragma unroll
    for (int e = 0; e < E_; e++) acc[e] = 0.f;
    for (int d = lane; d < D_; d += 64) {
        float v = xr[d];
        const float* g = gw + d * E_;
#pragma unroll
        for (int e = 0; e < E_; e++) acc[e] += v * g[e];
    }
#pragma unroll
    for (int e = 0; e < E_; e++) {
#pragma unroll
        for (int off = 32; off; off >>= 1) acc[e] += __shfl_xor(acc[e], off, 64);
    }
    if (lane == 0) {
        float v0 = -3.4e38f, v1 = -3.4e38f;
        int i0 = 0, i1 = 0;
#pragma unroll
        for (int e = 0; e < E_; e++) {
            float l = acc[e] + gb[e];
            if (l > v0) { v1 = v0; i1 = i0; v0 = l; i0 = e; }
            else if (l > v1) { v1 = l; i1 = e; }
        }
        float p1 = expf(v1 - v0);
        float s = 1.f + p1;
        int p0 = atomicAdd(&counts[i0], 1);
        list[i0 * N_TOK + p0] = tok * 2;
        int p1p = atomicAdd(&counts[i1], 1);
        list[i1 * N_TOK + p1p] = tok * 2 + 1;
        wslot[tok * 2] = 1.f / s;
        wslot[tok * 2 + 1] = p1 / s;
    }
}

__device__ __forceinline__ void kstep(const f16 A[][PADK], const f16 B[][PADK],
                                      int wr, int wc, int fr, int fk,
                                      f32x4 acc[4][4]) {
    f16x8 af[4], bf[4];
#pragma unroll
    for (int m = 0; m < 4; m++) af[m] = *(const f16x8*)&A[wr + m * 16 + fr][fk];
#pragma unroll
    for (int n = 0; n < 4; n++) bf[n] = *(const f16x8*)&B[wc + n * 16 + fr][fk];
#pragma unroll
    for (int m = 0; m < 4; m++)
#pragma unroll
        for (int n = 0; n < 4; n++)
            acc[m][n] = __builtin_amdgcn_mfma_f32_16x16x32_f16(af[m], bf[n], acc[m][n], 0, 0, 0);
}

// load tile chunk into named regs (per-lane global loads; reg deps enforce waits)
#define LOADT(kk, rA0, rA1, rB0, rB1) do {            \
    rA0 = *(const f16x8*)(aptr0 + (kk));              \
    rA1 = *(const f16x8*)(aptr1 + (kk));              \
    rB0 = *(const f16x8*)(bptr0 + (kk));              \
    rB1 = *(const f16x8*)(bptr1 + (kk));              \
} while (0)

#define WRITET(rA0, rA1, rB0, rB1) do {               \
    *(f16x8*)&Alds[sr0][sc] = rA0;                    \
    *(f16x8*)&Alds[sr1][sc] = rA1;                    \
    *(f16x8*)&Blds[sr0][sc] = rB0;                    \
    *(f16x8*)&Blds[sr1][sc] = rB1;                    \
} while (0)

// ---------------- GEMM1: h = gelu(x @ w1 + b1) ----------------
__global__ __launch_bounds__(256) void gemm1(const f16* __restrict__ xh,
                                             const f16* __restrict__ w1t,
                                             const float* __restrict__ b1,
                                             const int* __restrict__ counts,
                                             const int* __restrict__ list,
                                             f16* __restrict__ hbuf) {
    int e = blockIdx.z;
    int cnt = counts[e];
    int rb = blockIdx.y * BM;
    if (rb >= cnt) return;
    int cb = blockIdx.x * BN;

    __shared__ f16 Alds[BM][PADK];
    __shared__ f16 Blds[BN][PADK];
    __shared__ int ids[BM];

    int tid = threadIdx.x;
    int wv = tid >> 6, lane = tid & 63;
    if (tid < BM) {
        int idx = rb + tid;
        ids[tid] = (idx < cnt) ? list[e * N_TOK + idx] : -1;
    }
    __syncthreads();

    int q0 = wv * 2, q1 = q0 + 1;
    int sr0 = q0 * 16 + (lane >> 2), sr1 = q1 * 16 + (lane >> 2);
    int sc = (lane & 3) * 8;
    int id0 = ids[sr0], id1 = ids[sr1];
    int fb = ids[0];
    const f16* aptr0 = xh + (size_t)(((id0 >= 0) ? id0 : fb) >> 1) * D_ + sc;
    const f16* aptr1 = xh + (size_t)(((id1 >= 0) ? id1 : fb) >> 1) * D_ + sc;
    const f16* wbase = w1t + (size_t)e * H_ * D_;
    const f16* bptr0 = wbase + (size_t)(cb + sr0) * D_ + sc;
    const f16* bptr1 = wbase + (size_t)(cb + sr1) * D_ + sc;

    int wr = (wv >> 1) * 64, wc = (wv & 1) * 64;
    int fr = lane & 15, fk = (lane >> 4) * 8;

    f32x4 acc[4][4] = {};

    {
        f16x8 cA0, cA1, cB0, cB1;
        LOADT(0, cA0, cA1, cB0, cB1);
        WRITET(cA0, cA1, cB0, cB1);
    }
    __syncthreads();
#pragma unroll 1
    for (int t = 0; t < D_ / BK; ++t) {
        f16x8 nA0, nA1, nB0, nB1;
        bool more = (t + 1 < D_ / BK);
        if (more) LOADT((t + 1) * BK, nA0, nA1, nB0, nB1);
        kstep(Alds, Blds, wr, wc, fr, fk, acc);
        __syncthreads();
        if (more) WRITET(nA0, nA1, nB0, nB1);
        __syncthreads();
    }

#pragma unroll
    for (int n = 0; n < 4; n++) {
        int colg = cb + wc + n * 16 + fr;
        float bias = b1[e * H_ + colg];
#pragma unroll
        for (int m = 0; m < 4; m++) {
#pragma unroll
            for (int r = 0; r < 4; r++) {
                int rloc = wr + m * 16 + (lane >> 4) * 4 + r;
                int id = ids[rloc];
                if (id >= 0) {
                    float v = acc[m][n][r] + bias;
                    v = 0.5f * v * (1.f + erff(v * 0.70710678f));
                    hbuf[(size_t)id * H_ + colg] = (f16)v;
                }
            }
        }
    }
}

// ---------------- GEMM2: y = (h @ w2 + b2) * wslot, scatter-add ----------------
#define KSPLIT 2
#define KCH (H_ / KSPLIT)
__global__ __launch_bounds__(256) void gemm2(const f16* __restrict__ hbuf,
                                             const f16* __restrict__ w2t,
                                             const float* __restrict__ b2,
                                             const int* __restrict__ counts,
                                             const int* __restrict__ list,
                                             const float* __restrict__ wslot,
                                             float* __restrict__ out) {
    int e = blockIdx.z;
    int cnt = counts[e];
    int rb = blockIdx.y * BM;
    if (rb >= cnt) return;
    int cbz = blockIdx.x;
    int cb = (cbz % (D_ / BN)) * BN;
    int kz = cbz / (D_ / BN);
    int k0 = kz * KCH;

    __shared__ f16 Alds[BM][PADK];
    __shared__ f16 Blds[BN][PADK];
    __shared__ int ids[BM];

    int tid = threadIdx.x;
    int wv = tid >> 6, lane = tid & 63;
    if (tid < BM) {
        int idx = rb + tid;
        ids[tid] = (idx < cnt) ? list[e * N_TOK + idx] : -1;
    }
    __syncthreads();

    int q0 = wv * 2, q1 = q0 + 1;
    int sr0 = q0 * 16 + (lane >> 2), sr1 = q1 * 16 + (lane >> 2);
    int sc = (lane & 3) * 8;
    int id0 = ids[sr0], id1 = ids[sr1];
    int fb = ids[0];
    const f16* aptr0 = hbuf + (size_t)((id0 >= 0) ? id0 : fb) * H_ + k0 + sc;
    const f16* aptr1 = hbuf + (size_t)((id1 >= 0) ? id1 : fb) * H_ + k0 + sc;
    const f16* wbase = w2t + (size_t)e * D_ * H_;
    const f16* bptr0 = wbase + (size_t)(cb + sr0) * H_ + k0 + sc;
    const f16* bptr1 = wbase + (size_t)(cb + sr1) * H_ + k0 + sc;

    int wr = (wv >> 1) * 64, wc = (wv & 1) * 64;
    int fr = lane & 15, fk = (lane >> 4) * 8;

    f32x4 acc[4][4] = {};

    {
        f16x8 cA0, cA1, cB0, cB1;
        LOADT(0, cA0, cA1, cB0, cB1);
        WRITET(cA0, cA1, cB0, cB1);
    }
    __syncthreads();
#pragma unroll 1
    for (int t = 0; t < KCH / BK; ++t) {
        f16x8 nA0, nA1, nB0, nB1;
        bool more = (t + 1 < KCH / BK);
        if (more) LOADT((t + 1) * BK, nA0, nA1, nB0, nB1);
        kstep(Alds, Blds, wr, wc, fr, fk, acc);
        __syncthreads();
        if (more) WRITET(nA0, nA1, nB0, nB1);
        __syncthreads();
    }

#pragma unroll
    for (int n = 0; n < 4; n++) {
        int colg = cb + wc + n * 16 + fr;
        float bias = (kz == 0) ? b2[e * D_ + colg] : 0.f;
#pragma unroll
        for (int m = 0; m < 4; m++) {
#pragma unroll
            for (int r = 0; r < 4; r++) {
                int rloc = wr + m * 16 + (lane >> 4) * 4 + r;
                int id = ids[rloc];
                if (id >= 0) {
                    float w = wslot[id];
                    float v = (acc[m][n][r] + bias) * w;
                    atomicAdd(&out[(size_t)(id >> 1) * D_ + colg], v);
                }
            }
        }
    }
}

extern "C" void kernel_launch(void* const* d_in, const int* in_sizes, int n_in,
                              void* d_out, int out_size, void* d_ws, size_t ws_size,
                              hipStream_t stream) {
    const float* x = (const float*)d_in[0];
    const float* gate_w = (const float*)d_in[1];
    const float* gate_b = (const float*)d_in[2];
    const float* w1 = (const float*)d_in[3];
    const float* b1 = (const float*)d_in[4];
    const float* w2 = (const float*)d_in[5];
    const float* b2 = (const float*)d_in[6];
    float* out = (float*)d_out;

    char* ws = (char*)d_ws;
    int* counts = (int*)ws;                           // 256 B
    int* list = (int*)(ws + 1024);                    // 131072 B
    float* wslot = (float*)(ws + 132096);             // 32768 B
    f16* xh = (f16*)(ws + 196608);                    // 6291456 B
    f16* w1t = (f16*)(ws + 6488064);                  // 37748736 B
    f16* w2t = (f16*)(ws + 44236800);                 // 37748736 B
    f16* hbuf = (f16*)(ws + 81985536);                // 50331648 B

    hipMemsetAsync(counts, 0, 256, stream);
    hipMemsetAsync(out, 0, (size_t)out_size * sizeof(float), stream);

    cvt_x<<<1536, 256, 0, stream>>>(x, xh);
    router<<<1024, 256, 0, stream>>>(x, gate_w, gate_b, counts, list, wslot);
    cvt_w_t<<<dim3(H_ / 64, D_ / 64, E_), 256, 0, stream>>>(w1, w1t, D_, H_);
    cvt_w_t<<<dim3(D_ / 64, H_ / 64, E_), 256, 0, stream>>>(w2, w2t, H_, D_);
    gemm1<<<dim3(H_ / BN, N_TOK / BM, E_), 256, 0, stream>>>(xh, w1t, b1, counts, list, hbuf);
    gemm2<<<dim3((D_ / BN) * KSPLIT, N_TOK / BM, E_), 256, 0, stream>>>(hbuf, w2t, b2, counts, list, wslot, out);
}